// Round 2
// baseline (1848.399 us; speedup 1.0000x reference)
//
#include <hip/hip_runtime.h>
#include <cstdio>
#include <cstdint>

#define NN  8
#define CCH 256
#define HWP 25200
#define SS  2520
#define KCL 315
#define KNN 10

__device__ __forceinline__ unsigned fmap(float f) {
  unsigned u = __float_as_uint(f);
  return (u & 0x80000000u) ? ~u : (u | 0x80000000u);
}
__device__ __forceinline__ float funmap(unsigned u) {
  unsigned b = (u & 0x80000000u) ? (u & 0x7fffffffu) : ~u;
  return __uint_as_float(b);
}

// ---------------- K-1: transpose w1 [d][c] -> w1T [c][d] --------------------
__global__ __launch_bounds__(256) void k_w1t(const float* __restrict__ w1, float* __restrict__ w1T) {
  __shared__ float tile[32][33];
  const int bx = blockIdx.x * 32, by = blockIdx.y * 32;
  const int tx = threadIdx.x, ty = threadIdx.y;  // 32 x 8
  for (int r = 0; r < 32; r += 8)
    tile[ty + r][tx] = w1[(by + ty + r) * CCH + bx + tx];
  __syncthreads();
  for (int r = 0; r < 32; r += 8)
    w1T[(bx + ty + r) * CCH + by + tx] = tile[tx][ty + r];
}

// ---------------- K0: score net (64px x 256d tile GEMM) ---------------------
// 8x8 thread tile (the measured conflict-free layout). X operand read
// directly from global (VMEM/L1 path) instead of LDS: halves LDS-port
// pressure (2 ds_read_b128/thread/kk instead of 4), which was the binding
// pipe (VALUBusy==67% == 2048/3072 VALU/LDS cycle ratio).
__global__ __launch_bounds__(256) void k_score(
    const float* __restrict__ x, const float* __restrict__ w1T,
    const float* __restrict__ b1, const float* __restrict__ w2,
    const float* __restrict__ b2, const float* __restrict__ pri,
    float* __restrict__ scores)
{
  __shared__ float Wl[16 * 256];   // [kk][d]
  __shared__ float red[64 * 33];
  const int n = blockIdx.y, p0 = blockIdx.x * 64, tid = threadIdx.x;
  const int dt = tid & 31, pt = tid >> 5;
  int gpA = p0 + 4 * pt;      if (gpA > HWP - 4) gpA = HWP - 4;
  int gpB = p0 + 32 + 4 * pt; if (gpB > HWP - 4) gpB = HWP - 4;
  const float* xb = x + (size_t)n * CCH * HWP;
  float acc[8][8];
#pragma unroll
  for (int i = 0; i < 8; ++i)
#pragma unroll
    for (int j = 0; j < 8; ++j) acc[i][j] = 0.f;

  for (int c0 = 0; c0 < CCH; c0 += 16) {
    // stage W: flat contiguous copy (w1T is [c][d], contiguous in d)
    {
      const float4* src = (const float4*)(w1T + (size_t)c0 * CCH);
      float4* dst = (float4*)Wl;
#pragma unroll
      for (int i = 0; i < 4; ++i) dst[tid + 256 * i] = src[tid + 256 * i];
    }
    __syncthreads();
#pragma unroll
    for (int kk = 0; kk < 16; ++kk) {
      const size_t rb = (size_t)(c0 + kk) * HWP;
      const float4 x0 = *(const float4*)&xb[rb + gpA];
      const float4 x1 = *(const float4*)&xb[rb + gpB];
      const float4 w0 = *(const float4*)&Wl[kk * 256 + 4 * dt];
      const float4 w1v = *(const float4*)&Wl[kk * 256 + 128 + 4 * dt];
      const float a[8] = {w0.x, w0.y, w0.z, w0.w, w1v.x, w1v.y, w1v.z, w1v.w};
      const float b[8] = {x0.x, x0.y, x0.z, x0.w, x1.x, x1.y, x1.z, x1.w};
#pragma unroll
      for (int di = 0; di < 8; ++di)
#pragma unroll
        for (int pj = 0; pj < 8; ++pj) acc[di][pj] += a[di] * b[pj];
    }
    __syncthreads();
  }
  // epilogue: relu + dot with w2 over this thread's 8 d's
  float part[8];
#pragma unroll
  for (int pj = 0; pj < 8; ++pj) part[pj] = 0.f;
#pragma unroll
  for (int di = 0; di < 8; ++di) {
    int d = (di < 4) ? (4 * dt + di) : (128 + 4 * dt + di - 4);
    float bb = b1[d], wv = w2[d];
#pragma unroll
    for (int pj = 0; pj < 8; ++pj) {
      float h = acc[di][pj] + bb; h = h > 0.f ? h : 0.f;
      part[pj] += h * wv;
    }
  }
#pragma unroll
  for (int pj = 0; pj < 8; ++pj) {
    int px = (pj < 4) ? (4 * pt + pj) : (32 + 4 * pt + pj - 4);
    red[px * 33 + dt] = part[pj];
  }
  __syncthreads();
  if (tid < 64) {
    float s = b2[0];
#pragma unroll
    for (int g = 0; g < 32; ++g) s += red[tid * 33 + g];
    float sc = 1.f / (1.f + expf(-s));
    int p = p0 + tid;
    if (p < HWP) scores[n * HWP + p] = sc * pri[n * HWP + p];
  }
}

// ---------------- shared bitonic (4096 u64 desc, 1024 thr) ------------------
__device__ __forceinline__ void bitonic4096_desc(unsigned long long* keys, int tid) {
  for (int k = 2; k <= 4096; k <<= 1) {
    for (int j = k >> 1; j > 0; j >>= 1) {
      for (int i = tid; i < 4096; i += 1024) {
        int ixj = i ^ j;
        if (ixj > i) {
          unsigned long long a = keys[i], b = keys[ixj];
          bool up = ((i & k) == 0);
          if ((a < b) == up) { keys[i] = b; keys[ixj] = a; }
        }
      }
      __syncthreads();
    }
  }
}

// ---------------- K1: exact top-S sample (radix select + sort) --------------
__global__ __launch_bounds__(1024) void k_topk_sample(
    const float* __restrict__ scores, int* __restrict__ topk_idx, float* __restrict__ conf)
{
  __shared__ unsigned hist[256];
  __shared__ unsigned long long keys[4096];
  __shared__ unsigned sh_rank, sh_chosen;
  __shared__ int sh_cnt;
  const int n = blockIdx.x;
  const int tid = threadIdx.x;
  if (tid == 0) sh_rank = SS;
  __syncthreads();
  unsigned prefix = 0, pmask = 0;
  for (int shift = 24; shift >= 0; shift -= 8) {
    for (int b = tid; b < 256; b += 1024) hist[b] = 0;
    __syncthreads();
    for (int e = tid; e < HWP; e += 1024) {
      unsigned u = fmap(scores[n * HWP + e]);
      if ((u & pmask) == prefix) atomicAdd(&hist[(u >> shift) & 255u], 1u);
    }
    __syncthreads();
    if (tid == 0) {
      unsigned r = sh_rank, chosen = 0;
      for (int b = 255; b >= 0; --b) {
        unsigned cb = hist[b];
        if (cb < r) r -= cb; else { chosen = (unsigned)b; break; }
      }
      sh_rank = r; sh_chosen = chosen;
    }
    __syncthreads();
    prefix |= sh_chosen << shift;
    pmask  |= 0xFFu << shift;
    __syncthreads();
  }
  const unsigned uT = prefix;
  if (tid == 0) sh_cnt = 0;
  for (int i = tid; i < 4096; i += 1024) keys[i] = 0ULL;
  __syncthreads();
  for (int e = tid; e < HWP; e += 1024) {
    unsigned u = fmap(scores[n * HWP + e]);
    if (u >= uT) {
      int s = atomicAdd(&sh_cnt, 1);
      if (s < 4096) keys[s] = ((unsigned long long)u << 32) | (unsigned)(~(unsigned)e);
    }
  }
  __syncthreads();
  bitonic4096_desc(keys, tid);
  for (int t = tid; t < SS; t += 1024) {
    unsigned long long kv = keys[t];
    topk_idx[n * SS + t] = (int)(~(unsigned)kv);
    conf[n * SS + t] = funmap((unsigned)(kv >> 32));
  }
}

// ---------------- reductions ------------------------------------------------
__device__ __forceinline__ float block_sum256(float v, float* scratch) {
#pragma unroll
  for (int o = 32; o > 0; o >>= 1) v += __shfl_down(v, o);
  int wid = threadIdx.x >> 6, lane = threadIdx.x & 63;
  if (lane == 0) scratch[wid] = v;
  __syncthreads();
  float r = scratch[0] + scratch[1] + scratch[2] + scratch[3];
  __syncthreads();
  return r;
}

// ---------------- K2: gather + layernorm + conf + sq ------------------------
__global__ __launch_bounds__(256) void k_gather_ln(
    const float* __restrict__ x, const int* __restrict__ topk_idx,
    const float* __restrict__ conf, float* __restrict__ tokens, float* __restrict__ sq)
{
  __shared__ float scratch[4];
  const int t = blockIdx.x, n = blockIdx.y, c = threadIdx.x;
  const int p = topk_idx[n * SS + t];
  float v = x[(size_t)(n * CCH + c) * HWP + p];
  float mu = block_sum256(v, scratch) * (1.f / CCH);
  float d = v - mu;
  float var = block_sum256(d * d, scratch) * (1.f / CCH);
  float inv = 1.f / sqrtf(var + 1e-5f);
  float tok = d * inv * conf[n * SS + t];
  tokens[(size_t)(n * SS + t) * CCH + c] = tok;
  float s2 = block_sum256(tok * tok, scratch);
  if (c == 0) sq[n * SS + t] = s2;
}

// ---------------- K2b: transpose tokens [n][t][c] -> tokensT [n][c][t] ------
__global__ __launch_bounds__(256) void k_ttrans(
    const float* __restrict__ tokens, float* __restrict__ tokensT)
{
  __shared__ float tile[64][68];
  const int n = blockIdx.z, t0 = blockIdx.x * 64, cc0 = blockIdx.y * 64;
  const int tid = threadIdx.x;
  for (int l = tid; l < 1024; l += 256) {
    int tr = l >> 4, q = l & 15;
    int gt = t0 + tr;
    float4 v = {0.f, 0.f, 0.f, 0.f};
    if (gt < SS) v = *(const float4*)&tokens[(size_t)(n * SS + gt) * CCH + cc0 + 4 * q];
    *(float4*)&tile[tr][4 * q] = v;
  }
  __syncthreads();
  for (int l = tid; l < 1024; l += 256) {
    int cr = l >> 4, q = l & 15;
    int gt = t0 + 4 * q;
    if (gt <= SS - 4) {
      float4 v;
      v.x = tile[4 * q + 0][cr]; v.y = tile[4 * q + 1][cr];
      v.z = tile[4 * q + 2][cr]; v.w = tile[4 * q + 3][cr];
      *(float4*)&tokensT[(size_t)(n * CCH + cc0 + cr) * SS + gt] = v;
    }
  }
}

// ---------------- K3: gram GEMM -> d2 (symmetric, upper blocks only) --------
// No LDS staging, no main-loop barriers: A and B tiles read per-thread
// straight from tokensT (L2-resident, 2.6 MB/slice). Per-wave spans are
// 256B contiguous -> ~4 lines/instr coalescing; LDS port fully freed.
__global__ __launch_bounds__(256) void k_gram(
    const float* __restrict__ tokensT, const float* __restrict__ sq,
    float* __restrict__ d2, int* __restrict__ d2max)
{
  const int bi = blockIdx.y, bj = blockIdx.x, n = blockIdx.z;
  if (bj < bi) return;
  __shared__ float redm[256];
  const int i0 = bi * 128, j0 = bj * 128, tid = threadIdx.x;
  const int ti = tid & 15, tj = tid >> 4;
  // clamped column starts (SS%4==0 -> any float4 is entirely valid or
  // entirely OOB; OOB lanes' results are discarded by the <SS guards below)
  int giA = i0 + 4 * ti;      if (giA > SS - 4) giA = SS - 4;
  int giB = i0 + 64 + 4 * ti; if (giB > SS - 4) giB = SS - 4;
  int gjA = j0 + 4 * tj;      if (gjA > SS - 4) gjA = SS - 4;
  int gjB = j0 + 64 + 4 * tj; if (gjB > SS - 4) gjB = SS - 4;
  const float* tb = tokensT + (size_t)n * CCH * SS;
  float acc[8][8];
#pragma unroll
  for (int i = 0; i < 8; ++i)
#pragma unroll
    for (int j = 0; j < 8; ++j) acc[i][j] = 0.f;

#pragma unroll 4
  for (int c = 0; c < CCH; ++c) {
    const size_t rb = (size_t)c * SS;
    const float4 a0 = *(const float4*)&tb[rb + giA];
    const float4 a1 = *(const float4*)&tb[rb + giB];
    const float4 b0 = *(const float4*)&tb[rb + gjA];
    const float4 b1 = *(const float4*)&tb[rb + gjB];
    const float a[8] = {a0.x, a0.y, a0.z, a0.w, a1.x, a1.y, a1.z, a1.w};
    const float b[8] = {b0.x, b0.y, b0.z, b0.w, b1.x, b1.y, b1.z, b1.w};
#pragma unroll
    for (int ii = 0; ii < 8; ++ii)
#pragma unroll
      for (int jj = 0; jj < 8; ++jj) acc[ii][jj] += a[ii] * b[jj];
  }

  int gi[8], gj[8];
  float sqi[8], sqj[8];
#pragma unroll
  for (int ii = 0; ii < 8; ++ii) {
    gi[ii] = i0 + ((ii < 4) ? (4 * ti + ii) : (64 + 4 * ti + ii - 4));
    sqi[ii] = (gi[ii] < SS) ? sq[n * SS + gi[ii]] : 0.f;
    gj[ii] = j0 + ((ii < 4) ? (4 * tj + ii) : (64 + 4 * tj + ii - 4));
    sqj[ii] = (gj[ii] < SS) ? sq[n * SS + gj[ii]] : 0.f;
  }
  float outv[8][8];
  float mx = -3e38f;
#pragma unroll
  for (int ii = 0; ii < 8; ++ii)
#pragma unroll
    for (int jj = 0; jj < 8; ++jj) {
      float o = sqi[ii] + sqj[jj] - 2.f * acc[ii][jj];
      outv[ii][jj] = o;
      if (gi[ii] < SS && gj[jj] < SS) mx = fmaxf(mx, o);
    }
  // direct stores: rows gi, cols j-groups (contiguous float4s)
#pragma unroll
  for (int ii = 0; ii < 8; ++ii) {
    if (gi[ii] < SS) {
      size_t row = (size_t)(n * SS + gi[ii]) * SS;
      int jb0 = j0 + 4 * tj;
      float4 o0 = {outv[ii][0], outv[ii][1], outv[ii][2], outv[ii][3]};
      *(float4*)&d2[row + jb0] = o0;
      int jb1 = j0 + 64 + 4 * tj;
      if (jb1 < SS) {
        float4 o1 = {outv[ii][4], outv[ii][5], outv[ii][6], outv[ii][7]};
        *(float4*)&d2[row + jb1] = o1;
      }
    }
  }
  // mirror stores for off-diagonal blocks
  if (bi != bj) {
#pragma unroll
    for (int jj = 0; jj < 8; ++jj) {
      if (gj[jj] < SS) {
        size_t row = (size_t)(n * SS + gj[jj]) * SS;
        int ib0 = i0 + 4 * ti;
        float4 m0 = {outv[0][jj], outv[1][jj], outv[2][jj], outv[3][jj]};
        *(float4*)&d2[row + ib0] = m0;
        int ib1 = i0 + 64 + 4 * ti;
        if (ib1 < SS) {
          float4 m1 = {outv[4][jj], outv[5][jj], outv[6][jj], outv[7][jj]};
          *(float4*)&d2[row + ib1] = m1;
        }
      }
    }
  }
  redm[tid] = mx; __syncthreads();
  for (int s = 128; s > 0; s >>= 1) {
    if (tid < s) redm[tid] = fmaxf(redm[tid], redm[tid + s]);
    __syncthreads();
  }
  if (tid == 0) atomicMax(&d2max[n], __float_as_int(redm[0]));
}

// ---------------- K4: KNN density (wave per row, register top-10) -----------
__global__ __launch_bounds__(256) void k_knn(
    const float* __restrict__ d2, float* __restrict__ density)
{
  const int n = blockIdx.y;
  const int w = threadIdx.x >> 6, lane = threadIdx.x & 63;
  const int i = blockIdx.x * 4 + w;
  const float* dr = &d2[(size_t)(n * SS + i) * SS];
  float s[KNN];
#pragma unroll
  for (int k = 0; k < KNN; ++k) s[k] = 3e38f;
  for (int e = lane; e < SS; e += 64) {
    float t = dr[e];
#pragma unroll
    for (int k = 0; k < KNN; ++k) {
      float lo = fminf(s[k], t);
      t = fmaxf(s[k], t);
      s[k] = lo;
    }
  }
  float sum = 0.f;
  for (int r = 0; r < KNN; ++r) {
    float m = s[0];
#pragma unroll
    for (int o = 32; o > 0; o >>= 1) m = fminf(m, __shfl_xor(m, o));
    unsigned long long msk = __ballot(s[0] == m);
    int first = __ffsll(msk) - 1;
    if (lane == first) {
#pragma unroll
      for (int k = 0; k < KNN - 1; ++k) s[k] = s[k + 1];
      s[KNN - 1] = 3e38f;
    }
    sum += fmaxf(m, 1e-12f);
  }
  if (lane == 0) density[n * SS + i] = expf(-sum * (1.f / (KNN * CCH)));
}

// ---------------- K5: parent dist + cscore ----------------------------------
__global__ __launch_bounds__(256) void k_parent(
    const float* __restrict__ d2, const float* __restrict__ density,
    const int* __restrict__ d2max, float* __restrict__ cscore)
{
  __shared__ float swv[4];
  const int i = blockIdx.x, n = blockIdx.y, tid = threadIdx.x;
  const float di = density[n * SS + i];
  const float* dr = &d2[(size_t)(n * SS + i) * SS];
  float m = 3e38f;
  for (int e = tid; e < SS; e += 256) {
    float dj = density[n * SS + e];
    float v = dr[e];
    if (dj > di && v < m) m = v;
  }
#pragma unroll
  for (int o = 32; o > 0; o >>= 1) m = fminf(m, __shfl_down(m, o));
  int wid = tid >> 6, lane = tid & 63;
  if (lane == 0) swv[wid] = m;
  __syncthreads();
  if (tid == 0) {
    float mm = fminf(fminf(swv[0], swv[1]), fminf(swv[2], swv[3]));
    mm = fminf(mm, __int_as_float(d2max[n]));
    float pd = sqrtf(fmaxf(mm, 1e-12f)) * 0.0625f;
    cscore[n * SS + i] = pd * di;
  }
}

// ---------------- K6: top-K cluster centers ---------------------------------
__global__ __launch_bounds__(1024) void k_topk_centers(
    const float* __restrict__ cscore, int* __restrict__ index_down)
{
  __shared__ unsigned long long keys[4096];
  const int n = blockIdx.x, tid = threadIdx.x;
  for (int i = tid; i < 4096; i += 1024) {
    unsigned long long kv = 0ULL;
    if (i < SS) kv = ((unsigned long long)fmap(cscore[n * SS + i]) << 32) | (unsigned)(~(unsigned)i);
    keys[i] = kv;
  }
  __syncthreads();
  bitonic4096_desc(keys, tid);
  for (int t = tid; t < KCL; t += 1024)
    index_down[n * KCL + t] = (int)(~(unsigned)keys[t]);
}

// ---------------- K7: cluster assignment ------------------------------------
__global__ __launch_bounds__(256) void k_assign(
    const float* __restrict__ d2, const int* __restrict__ index_down,
    int* __restrict__ idx_cluster)
{
  const int n = blockIdx.y;
  const int i = blockIdx.x * 256 + threadIdx.x;
  if (i >= SS) return;
  float best = 3e38f; int bk = 0;
  for (int k = 0; k < KCL; ++k) {
    int r = index_down[n * KCL + k];
    float v = d2[(size_t)(n * SS + r) * SS + i];
    if (v < best) { best = v; bk = k; }
  }
  idx_cluster[n * SS + i] = bk;
}

__global__ void k_center_overwrite(const int* __restrict__ index_down, int* __restrict__ idx_cluster) {
  const int n = blockIdx.x; const int k = threadIdx.x;
  if (k < KCL) idx_cluster[n * SS + index_down[n * KCL + k]] = k;
}

// ---------------- K8/K9: merge ----------------------------------------------
__global__ __launch_bounds__(256) void k_weights(
    const int* __restrict__ idx_cluster, const float* __restrict__ conf, float* __restrict__ all_w)
{
  const int n = blockIdx.y; const int i = blockIdx.x * 256 + threadIdx.x;
  if (i >= SS) return;
  atomicAdd(&all_w[n * KCL + idx_cluster[n * SS + i]], conf[n * SS + i]);
}

__global__ __launch_bounds__(256) void k_merge(
    const int* __restrict__ idx_cluster, const float* __restrict__ conf,
    const float* __restrict__ all_w, const float* __restrict__ tokens, float* __restrict__ merged)
{
  const int t = blockIdx.x, n = blockIdx.y, c = threadIdx.x;
  const int k = idx_cluster[n * SS + t];
  const float w = conf[n * SS + t] / (all_w[n * KCL + k] + 1e-6f);
  atomicAdd(&merged[(size_t)(n * KCL + k) * CCH + c],
            tokens[(size_t)(n * SS + t) * CCH + c] * w);
}

// ---------------- K10: pixel -> cluster map ---------------------------------
__global__ __launch_bounds__(256) void k_kmap(
    const int* __restrict__ topk_idx, const int* __restrict__ idx_cluster, int* __restrict__ kmap)
{
  const int n = blockIdx.y; const int i = blockIdx.x * 256 + threadIdx.x;
  if (i >= SS) return;
  kmap[n * HWP + topk_idx[n * SS + i]] = idx_cluster[n * SS + i];
}

// ---------------- K11: ego flags --------------------------------------------
__global__ void k_ego(const int* __restrict__ record_len, int R, int* __restrict__ ego) {
  if (threadIdx.x == 0 && blockIdx.x == 0) {
    int acc = 0;
    for (int r = 0; r < R; ++r) {
      if (acc >= 0 && acc < NN) ego[acc] = 1;
      acc += record_len[r];
    }
  }
}

// ---------------- K12: final output (float4) --------------------------------
__global__ __launch_bounds__(256) void k_output(
    const float* __restrict__ x, const float* __restrict__ merged,
    const int* __restrict__ kmap, const int* __restrict__ ego, float* __restrict__ out)
{
  const int n = blockIdx.z, c = blockIdx.y;
  const int p4 = blockIdx.x * 256 + threadIdx.x;
  if (p4 >= HWP / 4) return;
  const size_t base = (size_t)(n * CCH + c) * HWP + 4 * p4;
  float4 v;
  if (ego[n]) {
    v = *(const float4*)&x[base];
  } else {
    int4 k4 = *(const int4*)&kmap[n * HWP + 4 * p4];
    const float* mb = &merged[(size_t)n * KCL * CCH + c];
    v.x = (k4.x >= 0) ? mb[(size_t)k4.x * CCH] : 0.f;
    v.y = (k4.y >= 0) ? mb[(size_t)k4.y * CCH] : 0.f;
    v.z = (k4.z >= 0) ? mb[(size_t)k4.z * CCH] : 0.f;
    v.w = (k4.w >= 0) ? mb[(size_t)k4.w * CCH] : 0.f;
  }
  *(float4*)&out[base] = v;
}

// ---------------- launch -----------------------------------------------------
extern "C" void kernel_launch(void* const* d_in, const int* in_sizes, int n_in,
                              void* d_out, int out_size, void* d_ws, size_t ws_size,
                              hipStream_t stream)
{
  const float* x   = (const float*)d_in[0];
  const float* w1  = (const float*)d_in[1];
  const float* b1  = (const float*)d_in[2];
  const float* w2  = (const float*)d_in[3];
  const float* b2  = (const float*)d_in[4];
  const float* pri = (const float*)d_in[5];
  const int*   rec = (const int*)d_in[6];
  const int R = in_sizes[6];
  float* out = (float*)d_out;

  char* ws = (char*)d_ws;
  size_t off = 0;
  auto alloc = [&](size_t bytes) -> char* {
    char* p = ws + off;
    off = (off + bytes + 255) & ~(size_t)255;
    return p;
  };
  float* scores      = (float*)alloc(sizeof(float) * NN * HWP);
  int*   topk_idx    = (int*)  alloc(sizeof(int)   * NN * SS);
  float* conf        = (float*)alloc(sizeof(float) * NN * SS);
  float* tokens      = (float*)alloc(sizeof(float) * (size_t)NN * SS * CCH);
  float* tokensT     = (float*)alloc(sizeof(float) * (size_t)NN * CCH * SS);
  float* w1T         = (float*)alloc(sizeof(float) * CCH * CCH);
  float* sq          = (float*)alloc(sizeof(float) * NN * SS);
  float* density     = (float*)alloc(sizeof(float) * NN * SS);
  float* cscore      = (float*)alloc(sizeof(float) * NN * SS);
  int*   d2max       = (int*)  alloc(sizeof(int)   * NN);
  int*   index_down  = (int*)  alloc(sizeof(int)   * NN * KCL);
  int*   idx_cluster = (int*)  alloc(sizeof(int)   * NN * SS);
  float* all_w       = (float*)alloc(sizeof(float) * NN * KCL);
  float* merged      = (float*)alloc(sizeof(float) * (size_t)NN * KCL * CCH);
  int*   kmap        = (int*)  alloc(sizeof(int)   * NN * HWP);
  int*   ego         = (int*)  alloc(sizeof(int)   * NN);
  float* d2          = (float*)alloc(sizeof(float) * (size_t)NN * SS * SS);
  if (off > ws_size)
    fprintf(stderr, "ERMVP kernel: workspace too small: need %zu, have %zu\n", off, ws_size);

  hipMemsetAsync(d2max, 0, sizeof(int) * NN, stream);
  hipMemsetAsync(all_w, 0, sizeof(float) * NN * KCL, stream);
  hipMemsetAsync(merged, 0, sizeof(float) * (size_t)NN * KCL * CCH, stream);
  hipMemsetAsync(kmap, 0xFF, sizeof(int) * NN * HWP, stream);
  hipMemsetAsync(ego, 0, sizeof(int) * NN, stream);

  k_w1t<<<dim3(8, 8), dim3(32, 8), 0, stream>>>(w1, w1T);
  k_score<<<dim3((HWP + 63) / 64, NN), 256, 0, stream>>>(x, w1T, b1, w2, b2, pri, scores);
  k_topk_sample<<<NN, 1024, 0, stream>>>(scores, topk_idx, conf);
  k_gather_ln<<<dim3(SS, NN), 256, 0, stream>>>(x, topk_idx, conf, tokens, sq);
  k_ttrans<<<dim3((SS + 63) / 64, CCH / 64, NN), 256, 0, stream>>>(tokens, tokensT);
  k_gram<<<dim3(20, 20, NN), 256, 0, stream>>>(tokensT, sq, d2, d2max);
  k_knn<<<dim3(SS / 4, NN), 256, 0, stream>>>(d2, density);
  k_parent<<<dim3(SS, NN), 256, 0, stream>>>(d2, density, d2max, cscore);
  k_topk_centers<<<NN, 1024, 0, stream>>>(cscore, index_down);
  k_assign<<<dim3((SS + 255) / 256, NN), 256, 0, stream>>>(d2, index_down, idx_cluster);
  k_center_overwrite<<<NN, 320, 0, stream>>>(index_down, idx_cluster);
  k_weights<<<dim3((SS + 255) / 256, NN), 256, 0, stream>>>(idx_cluster, conf, all_w);
  k_merge<<<dim3(SS, NN), 256, 0, stream>>>(idx_cluster, conf, all_w, tokens, merged);
  k_kmap<<<dim3((SS + 255) / 256, NN), 256, 0, stream>>>(topk_idx, idx_cluster, kmap);
  k_ego<<<1, 64, 0, stream>>>(rec, R, ego);
  k_output<<<dim3((HWP / 4 + 255) / 256, CCH, NN), 256, 0, stream>>>(x, merged, kmap, ego, out);
}

// Round 3
// 1572.615 us; speedup vs baseline: 1.1754x; 1.1754x over previous
//
#include <hip/hip_runtime.h>
#include <cstdio>
#include <cstdint>

#define NN  8
#define CCH 256
#define HWP 25200
#define SS  2520
#define KCL 315
#define KNN 10

__device__ __forceinline__ unsigned fmap(float f) {
  unsigned u = __float_as_uint(f);
  return (u & 0x80000000u) ? ~u : (u | 0x80000000u);
}
__device__ __forceinline__ float funmap(unsigned u) {
  unsigned b = (u & 0x80000000u) ? (u & 0x7fffffffu) : ~u;
  return __uint_as_float(b);
}

// ---------------- K-1: transpose w1 [d][c] -> w1T [c][d] --------------------
__global__ __launch_bounds__(256) void k_w1t(const float* __restrict__ w1, float* __restrict__ w1T) {
  __shared__ float tile[32][33];
  const int bx = blockIdx.x * 32, by = blockIdx.y * 32;
  const int tx = threadIdx.x, ty = threadIdx.y;  // 32 x 8
  for (int r = 0; r < 32; r += 8)
    tile[ty + r][tx] = w1[(by + ty + r) * CCH + bx + tx];
  __syncthreads();
  for (int r = 0; r < 32; r += 8)
    w1T[(bx + ty + r) * CCH + by + tx] = tile[tx][ty + r];
}

// ---------------- K0: score net (64px x 256d tile GEMM) ---------------------
// R0 structure (8x8 thread tile, conflict-free LDS patterns) + double-buffered
// staging: issue next-chunk global loads BEFORE compute, ds_write to alternate
// buffer AFTER compute, ONE barrier per chunk. Global latency hides under
// ~2048 cyc of FMAs per chunk.
__global__ __launch_bounds__(256) void k_score(
    const float* __restrict__ x, const float* __restrict__ w1T,
    const float* __restrict__ b1, const float* __restrict__ w2,
    const float* __restrict__ b2, const float* __restrict__ pri,
    float* __restrict__ scores)
{
  __shared__ float Wl[2][16 * 256];   // [buf][kk*256+d]  32 KB
  __shared__ float Xl[2][16 * 64];    // [buf][kk*64+p]    8 KB
  const int n = blockIdx.y, p0 = blockIdx.x * 64, tid = threadIdx.x;
  const int dt = tid & 31, pt = tid >> 5;
  const int skk = tid >> 4, sq = tid & 15;           // X staging coords
  int sgp = p0 + 4 * sq; if (sgp > HWP - 4) sgp = HWP - 4;
  const float* xb = x + (size_t)n * CCH * HWP;

  float acc[8][8];
#pragma unroll
  for (int i = 0; i < 8; ++i)
#pragma unroll
    for (int j = 0; j < 8; ++j) acc[i][j] = 0.f;

  // prologue: stage chunk 0 into buffer 0
  {
    const float4* src = (const float4*)w1T;
    float4* dst = (float4*)Wl[0];
#pragma unroll
    for (int i = 0; i < 4; ++i) dst[tid + 256 * i] = src[tid + 256 * i];
    *(float4*)&Xl[0][skk * 64 + 4 * sq] = *(const float4*)&xb[(size_t)skk * HWP + sgp];
  }
  __syncthreads();

  for (int c0 = 0; c0 < CCH; c0 += 16) {
    const int cur = (c0 >> 4) & 1;
    const bool nxt = (c0 + 16) < CCH;
    float4 wr0, wr1, wr2, wr3, xr;
    if (nxt) {  // issue-early: loads in flight during compute
      const float4* src = (const float4*)(w1T + (size_t)(c0 + 16) * CCH);
      wr0 = src[tid];       wr1 = src[tid + 256];
      wr2 = src[tid + 512]; wr3 = src[tid + 768];
      xr = *(const float4*)&xb[(size_t)(c0 + 16 + skk) * HWP + sgp];
    }
#pragma unroll
    for (int kk = 0; kk < 16; ++kk) {
      const float4 w0 = *(const float4*)&Wl[cur][kk * 256 + 4 * dt];
      const float4 w1v = *(const float4*)&Wl[cur][kk * 256 + 128 + 4 * dt];
      const float4 x0 = *(const float4*)&Xl[cur][kk * 64 + 4 * pt];
      const float4 x1 = *(const float4*)&Xl[cur][kk * 64 + 32 + 4 * pt];
      const float a[8] = {w0.x, w0.y, w0.z, w0.w, w1v.x, w1v.y, w1v.z, w1v.w};
      const float b[8] = {x0.x, x0.y, x0.z, x0.w, x1.x, x1.y, x1.z, x1.w};
#pragma unroll
      for (int di = 0; di < 8; ++di)
#pragma unroll
        for (int pj = 0; pj < 8; ++pj) acc[di][pj] += a[di] * b[pj];
    }
    if (nxt) {  // write-late: latency already covered by the FMA block
      float4* dst = (float4*)Wl[cur ^ 1];
      dst[tid] = wr0;       dst[tid + 256] = wr1;
      dst[tid + 512] = wr2; dst[tid + 768] = wr3;
      *(float4*)&Xl[cur ^ 1][skk * 64 + 4 * sq] = xr;
    }
    __syncthreads();   // single barrier per chunk
  }

  // epilogue: relu + dot with w2 over this thread's 8 d's
  float* red = &Wl[0][0];   // overlay scratch on Wl (all reads done)
  float part[8];
#pragma unroll
  for (int pj = 0; pj < 8; ++pj) part[pj] = 0.f;
#pragma unroll
  for (int di = 0; di < 8; ++di) {
    int d = (di < 4) ? (4 * dt + di) : (128 + 4 * dt + di - 4);
    float bb = b1[d], wv = w2[d];
#pragma unroll
    for (int pj = 0; pj < 8; ++pj) {
      float h = acc[di][pj] + bb; h = h > 0.f ? h : 0.f;
      part[pj] += h * wv;
    }
  }
#pragma unroll
  for (int pj = 0; pj < 8; ++pj) {
    int px = (pj < 4) ? (4 * pt + pj) : (32 + 4 * pt + pj - 4);
    red[px * 33 + dt] = part[pj];
  }
  __syncthreads();
  if (tid < 64) {
    float s = b2[0];
#pragma unroll
    for (int g = 0; g < 32; ++g) s += red[tid * 33 + g];
    float sc = 1.f / (1.f + expf(-s));
    int p = p0 + tid;
    if (p < HWP) scores[n * HWP + p] = sc * pri[n * HWP + p];
  }
}

// ---------------- shared bitonic (4096 u64 desc, 1024 thr) ------------------
__device__ __forceinline__ void bitonic4096_desc(unsigned long long* keys, int tid) {
  for (int k = 2; k <= 4096; k <<= 1) {
    for (int j = k >> 1; j > 0; j >>= 1) {
      for (int i = tid; i < 4096; i += 1024) {
        int ixj = i ^ j;
        if (ixj > i) {
          unsigned long long a = keys[i], b = keys[ixj];
          bool up = ((i & k) == 0);
          if ((a < b) == up) { keys[i] = b; keys[ixj] = a; }
        }
      }
      __syncthreads();
    }
  }
}

// ---------------- K1: exact top-S sample (radix select + sort) --------------
__global__ __launch_bounds__(1024) void k_topk_sample(
    const float* __restrict__ scores, int* __restrict__ topk_idx, float* __restrict__ conf)
{
  __shared__ unsigned hist[256];
  __shared__ unsigned long long keys[4096];
  __shared__ unsigned sh_rank, sh_chosen;
  __shared__ int sh_cnt;
  const int n = blockIdx.x;
  const int tid = threadIdx.x;
  if (tid == 0) sh_rank = SS;
  __syncthreads();
  unsigned prefix = 0, pmask = 0;
  for (int shift = 24; shift >= 0; shift -= 8) {
    for (int b = tid; b < 256; b += 1024) hist[b] = 0;
    __syncthreads();
    for (int e = tid; e < HWP; e += 1024) {
      unsigned u = fmap(scores[n * HWP + e]);
      if ((u & pmask) == prefix) atomicAdd(&hist[(u >> shift) & 255u], 1u);
    }
    __syncthreads();
    if (tid == 0) {
      unsigned r = sh_rank, chosen = 0;
      for (int b = 255; b >= 0; --b) {
        unsigned cb = hist[b];
        if (cb < r) r -= cb; else { chosen = (unsigned)b; break; }
      }
      sh_rank = r; sh_chosen = chosen;
    }
    __syncthreads();
    prefix |= sh_chosen << shift;
    pmask  |= 0xFFu << shift;
    __syncthreads();
  }
  const unsigned uT = prefix;
  if (tid == 0) sh_cnt = 0;
  for (int i = tid; i < 4096; i += 1024) keys[i] = 0ULL;
  __syncthreads();
  for (int e = tid; e < HWP; e += 1024) {
    unsigned u = fmap(scores[n * HWP + e]);
    if (u >= uT) {
      int s = atomicAdd(&sh_cnt, 1);
      if (s < 4096) keys[s] = ((unsigned long long)u << 32) | (unsigned)(~(unsigned)e);
    }
  }
  __syncthreads();
  bitonic4096_desc(keys, tid);
  for (int t = tid; t < SS; t += 1024) {
    unsigned long long kv = keys[t];
    topk_idx[n * SS + t] = (int)(~(unsigned)kv);
    conf[n * SS + t] = funmap((unsigned)(kv >> 32));
  }
}

// ---------------- reductions ------------------------------------------------
__device__ __forceinline__ float block_sum256(float v, float* scratch) {
#pragma unroll
  for (int o = 32; o > 0; o >>= 1) v += __shfl_down(v, o);
  int wid = threadIdx.x >> 6, lane = threadIdx.x & 63;
  if (lane == 0) scratch[wid] = v;
  __syncthreads();
  float r = scratch[0] + scratch[1] + scratch[2] + scratch[3];
  __syncthreads();
  return r;
}

// ---------------- K2: gather + layernorm + conf + sq ------------------------
__global__ __launch_bounds__(256) void k_gather_ln(
    const float* __restrict__ x, const int* __restrict__ topk_idx,
    const float* __restrict__ conf, float* __restrict__ tokens, float* __restrict__ sq)
{
  __shared__ float scratch[4];
  const int t = blockIdx.x, n = blockIdx.y, c = threadIdx.x;
  const int p = topk_idx[n * SS + t];
  float v = x[(size_t)(n * CCH + c) * HWP + p];
  float mu = block_sum256(v, scratch) * (1.f / CCH);
  float d = v - mu;
  float var = block_sum256(d * d, scratch) * (1.f / CCH);
  float inv = 1.f / sqrtf(var + 1e-5f);
  float tok = d * inv * conf[n * SS + t];
  tokens[(size_t)(n * SS + t) * CCH + c] = tok;
  float s2 = block_sum256(tok * tok, scratch);
  if (c == 0) sq[n * SS + t] = s2;
}

// ---------------- K2b: transpose tokens [n][t][c] -> tokensT [n][c][t] ------
__global__ __launch_bounds__(256) void k_ttrans(
    const float* __restrict__ tokens, float* __restrict__ tokensT)
{
  __shared__ float tile[64][68];
  const int n = blockIdx.z, t0 = blockIdx.x * 64, cc0 = blockIdx.y * 64;
  const int tid = threadIdx.x;
  for (int l = tid; l < 1024; l += 256) {
    int tr = l >> 4, q = l & 15;
    int gt = t0 + tr;
    float4 v = {0.f, 0.f, 0.f, 0.f};
    if (gt < SS) v = *(const float4*)&tokens[(size_t)(n * SS + gt) * CCH + cc0 + 4 * q];
    *(float4*)&tile[tr][4 * q] = v;
  }
  __syncthreads();
  for (int l = tid; l < 1024; l += 256) {
    int cr = l >> 4, q = l & 15;
    int gt = t0 + 4 * q;
    if (gt <= SS - 4) {
      float4 v;
      v.x = tile[4 * q + 0][cr]; v.y = tile[4 * q + 1][cr];
      v.z = tile[4 * q + 2][cr]; v.w = tile[4 * q + 3][cr];
      *(float4*)&tokensT[(size_t)(n * CCH + cc0 + cr) * SS + gt] = v;
    }
  }
}

// ---------------- K3: gram GEMM -> d2 (symmetric, upper blocks only) --------
// R0 LDS structure + the same double-buffered single-barrier schedule.
__global__ __launch_bounds__(256) void k_gram(
    const float* __restrict__ tokensT, const float* __restrict__ sq,
    float* __restrict__ d2, int* __restrict__ d2max)
{
  const int bi = blockIdx.y, bj = blockIdx.x, n = blockIdx.z;
  if (bj < bi) return;
  __shared__ float Al[2][16 * 128], Bl[2][16 * 128];  // 32 KB total
  const int i0 = bi * 128, j0 = bj * 128, tid = threadIdx.x;
  const int ti = tid & 15, tj = tid >> 4;
  const int skk = tid >> 5, sq4 = (tid & 31) * 4;     // staging coords (rows skk, skk+8)
  const int giS = i0 + sq4, gjS = j0 + sq4;
  const float* tb = tokensT + (size_t)n * CCH * SS;
  const float4 z4 = {0.f, 0.f, 0.f, 0.f};
  float acc[8][8];
#pragma unroll
  for (int i = 0; i < 8; ++i)
#pragma unroll
    for (int j = 0; j < 8; ++j) acc[i][j] = 0.f;

  // prologue: stage chunk 0
  {
    size_t r0 = (size_t)skk * SS, r1 = (size_t)(skk + 8) * SS;
    *(float4*)&Al[0][skk * 128 + sq4]       = (giS <= SS - 4) ? *(const float4*)&tb[r0 + giS] : z4;
    *(float4*)&Al[0][(skk + 8) * 128 + sq4] = (giS <= SS - 4) ? *(const float4*)&tb[r1 + giS] : z4;
    *(float4*)&Bl[0][skk * 128 + sq4]       = (gjS <= SS - 4) ? *(const float4*)&tb[r0 + gjS] : z4;
    *(float4*)&Bl[0][(skk + 8) * 128 + sq4] = (gjS <= SS - 4) ? *(const float4*)&tb[r1 + gjS] : z4;
  }
  __syncthreads();

  for (int c0 = 0; c0 < CCH; c0 += 16) {
    const int cur = (c0 >> 4) & 1;
    const bool nxt = (c0 + 16) < CCH;
    float4 a0r, a1r, b0r, b1r;
    if (nxt) {
      size_t r0 = (size_t)(c0 + 16 + skk) * SS, r1 = (size_t)(c0 + 24 + skk) * SS;
      a0r = (giS <= SS - 4) ? *(const float4*)&tb[r0 + giS] : z4;
      a1r = (giS <= SS - 4) ? *(const float4*)&tb[r1 + giS] : z4;
      b0r = (gjS <= SS - 4) ? *(const float4*)&tb[r0 + gjS] : z4;
      b1r = (gjS <= SS - 4) ? *(const float4*)&tb[r1 + gjS] : z4;
    }
#pragma unroll
    for (int kk = 0; kk < 16; ++kk) {
      const float4 a0 = *(const float4*)&Al[cur][kk * 128 + 4 * ti];
      const float4 a1 = *(const float4*)&Al[cur][kk * 128 + 64 + 4 * ti];
      const float4 b0 = *(const float4*)&Bl[cur][kk * 128 + 4 * tj];
      const float4 b1 = *(const float4*)&Bl[cur][kk * 128 + 64 + 4 * tj];
      const float a[8] = {a0.x, a0.y, a0.z, a0.w, a1.x, a1.y, a1.z, a1.w};
      const float b[8] = {b0.x, b0.y, b0.z, b0.w, b1.x, b1.y, b1.z, b1.w};
#pragma unroll
      for (int ii = 0; ii < 8; ++ii)
#pragma unroll
        for (int jj = 0; jj < 8; ++jj) acc[ii][jj] += a[ii] * b[jj];
    }
    if (nxt) {
      *(float4*)&Al[cur ^ 1][skk * 128 + sq4]       = a0r;
      *(float4*)&Al[cur ^ 1][(skk + 8) * 128 + sq4] = a1r;
      *(float4*)&Bl[cur ^ 1][skk * 128 + sq4]       = b0r;
      *(float4*)&Bl[cur ^ 1][(skk + 8) * 128 + sq4] = b1r;
    }
    __syncthreads();
  }

  int gi[8], gj[8];
  float sqi[8], sqj[8];
#pragma unroll
  for (int ii = 0; ii < 8; ++ii) {
    gi[ii] = i0 + ((ii < 4) ? (4 * ti + ii) : (64 + 4 * ti + ii - 4));
    sqi[ii] = (gi[ii] < SS) ? sq[n * SS + gi[ii]] : 0.f;
    gj[ii] = j0 + ((ii < 4) ? (4 * tj + ii) : (64 + 4 * tj + ii - 4));
    sqj[ii] = (gj[ii] < SS) ? sq[n * SS + gj[ii]] : 0.f;
  }
  float outv[8][8];
  float mx = -3e38f;
#pragma unroll
  for (int ii = 0; ii < 8; ++ii)
#pragma unroll
    for (int jj = 0; jj < 8; ++jj) {
      float o = sqi[ii] + sqj[jj] - 2.f * acc[ii][jj];
      outv[ii][jj] = o;
      if (gi[ii] < SS && gj[jj] < SS) mx = fmaxf(mx, o);
    }
  // direct stores: rows gi, cols j-groups (contiguous float4s)
#pragma unroll
  for (int ii = 0; ii < 8; ++ii) {
    if (gi[ii] < SS) {
      size_t row = (size_t)(n * SS + gi[ii]) * SS;
      int jb0 = j0 + 4 * tj;
      float4 o0 = {outv[ii][0], outv[ii][1], outv[ii][2], outv[ii][3]};
      *(float4*)&d2[row + jb0] = o0;
      int jb1 = j0 + 64 + 4 * tj;
      if (jb1 < SS) {
        float4 o1 = {outv[ii][4], outv[ii][5], outv[ii][6], outv[ii][7]};
        *(float4*)&d2[row + jb1] = o1;
      }
    }
  }
  // mirror stores for off-diagonal blocks
  if (bi != bj) {
#pragma unroll
    for (int jj = 0; jj < 8; ++jj) {
      if (gj[jj] < SS) {
        size_t row = (size_t)(n * SS + gj[jj]) * SS;
        int ib0 = i0 + 4 * ti;
        float4 m0 = {outv[0][jj], outv[1][jj], outv[2][jj], outv[3][jj]};
        *(float4*)&d2[row + ib0] = m0;
        int ib1 = i0 + 64 + 4 * ti;
        if (ib1 < SS) {
          float4 m1 = {outv[4][jj], outv[5][jj], outv[6][jj], outv[7][jj]};
          *(float4*)&d2[row + ib1] = m1;
        }
      }
    }
  }
  float* redm = &Al[0][0];  // overlay (all LDS reads done)
  redm[tid] = mx; __syncthreads();
  for (int s = 128; s > 0; s >>= 1) {
    if (tid < s) redm[tid] = fmaxf(redm[tid], redm[tid + s]);
    __syncthreads();
  }
  if (tid == 0) atomicMax(&d2max[n], __float_as_int(redm[0]));
}

// ---------------- K4: KNN density (wave per row, register top-10) -----------
__global__ __launch_bounds__(256) void k_knn(
    const float* __restrict__ d2, float* __restrict__ density)
{
  const int n = blockIdx.y;
  const int w = threadIdx.x >> 6, lane = threadIdx.x & 63;
  const int i = blockIdx.x * 4 + w;
  const float* dr = &d2[(size_t)(n * SS + i) * SS];
  float s[KNN];
#pragma unroll
  for (int k = 0; k < KNN; ++k) s[k] = 3e38f;
  for (int e = lane; e < SS; e += 64) {
    float t = dr[e];
#pragma unroll
    for (int k = 0; k < KNN; ++k) {
      float lo = fminf(s[k], t);
      t = fmaxf(s[k], t);
      s[k] = lo;
    }
  }
  float sum = 0.f;
  for (int r = 0; r < KNN; ++r) {
    float m = s[0];
#pragma unroll
    for (int o = 32; o > 0; o >>= 1) m = fminf(m, __shfl_xor(m, o));
    unsigned long long msk = __ballot(s[0] == m);
    int first = __ffsll(msk) - 1;
    if (lane == first) {
#pragma unroll
      for (int k = 0; k < KNN - 1; ++k) s[k] = s[k + 1];
      s[KNN - 1] = 3e38f;
    }
    sum += fmaxf(m, 1e-12f);
  }
  if (lane == 0) density[n * SS + i] = expf(-sum * (1.f / (KNN * CCH)));
}

// ---------------- K5: parent dist + cscore ----------------------------------
__global__ __launch_bounds__(256) void k_parent(
    const float* __restrict__ d2, const float* __restrict__ density,
    const int* __restrict__ d2max, float* __restrict__ cscore)
{
  __shared__ float swv[4];
  const int i = blockIdx.x, n = blockIdx.y, tid = threadIdx.x;
  const float di = density[n * SS + i];
  const float* dr = &d2[(size_t)(n * SS + i) * SS];
  float m = 3e38f;
  for (int e = tid; e < SS; e += 256) {
    float dj = density[n * SS + e];
    float v = dr[e];
    if (dj > di && v < m) m = v;
  }
#pragma unroll
  for (int o = 32; o > 0; o >>= 1) m = fminf(m, __shfl_down(m, o));
  int wid = tid >> 6, lane = tid & 63;
  if (lane == 0) swv[wid] = m;
  __syncthreads();
  if (tid == 0) {
    float mm = fminf(fminf(swv[0], swv[1]), fminf(swv[2], swv[3]));
    mm = fminf(mm, __int_as_float(d2max[n]));
    float pd = sqrtf(fmaxf(mm, 1e-12f)) * 0.0625f;
    cscore[n * SS + i] = pd * di;
  }
}

// ---------------- K6: top-K cluster centers ---------------------------------
__global__ __launch_bounds__(1024) void k_topk_centers(
    const float* __restrict__ cscore, int* __restrict__ index_down)
{
  __shared__ unsigned long long keys[4096];
  const int n = blockIdx.x, tid = threadIdx.x;
  for (int i = tid; i < 4096; i += 1024) {
    unsigned long long kv = 0ULL;
    if (i < SS) kv = ((unsigned long long)fmap(cscore[n * SS + i]) << 32) | (unsigned)(~(unsigned)i);
    keys[i] = kv;
  }
  __syncthreads();
  bitonic4096_desc(keys, tid);
  for (int t = tid; t < KCL; t += 1024)
    index_down[n * KCL + t] = (int)(~(unsigned)keys[t]);
}

// ---------------- K7: cluster assignment ------------------------------------
__global__ __launch_bounds__(256) void k_assign(
    const float* __restrict__ d2, const int* __restrict__ index_down,
    int* __restrict__ idx_cluster)
{
  const int n = blockIdx.y;
  const int i = blockIdx.x * 256 + threadIdx.x;
  if (i >= SS) return;
  float best = 3e38f; int bk = 0;
  for (int k = 0; k < KCL; ++k) {
    int r = index_down[n * KCL + k];
    float v = d2[(size_t)(n * SS + r) * SS + i];
    if (v < best) { best = v; bk = k; }
  }
  idx_cluster[n * SS + i] = bk;
}

__global__ void k_center_overwrite(const int* __restrict__ index_down, int* __restrict__ idx_cluster) {
  const int n = blockIdx.x; const int k = threadIdx.x;
  if (k < KCL) idx_cluster[n * SS + index_down[n * KCL + k]] = k;
}

// ---------------- K8/K9: merge ----------------------------------------------
__global__ __launch_bounds__(256) void k_weights(
    const int* __restrict__ idx_cluster, const float* __restrict__ conf, float* __restrict__ all_w)
{
  const int n = blockIdx.y; const int i = blockIdx.x * 256 + threadIdx.x;
  if (i >= SS) return;
  atomicAdd(&all_w[n * KCL + idx_cluster[n * SS + i]], conf[n * SS + i]);
}

__global__ __launch_bounds__(256) void k_merge(
    const int* __restrict__ idx_cluster, const float* __restrict__ conf,
    const float* __restrict__ all_w, const float* __restrict__ tokens, float* __restrict__ merged)
{
  const int t = blockIdx.x, n = blockIdx.y, c = threadIdx.x;
  const int k = idx_cluster[n * SS + t];
  const float w = conf[n * SS + t] / (all_w[n * KCL + k] + 1e-6f);
  atomicAdd(&merged[(size_t)(n * KCL + k) * CCH + c],
            tokens[(size_t)(n * SS + t) * CCH + c] * w);
}

// ---------------- K10: pixel -> cluster map ---------------------------------
__global__ __launch_bounds__(256) void k_kmap(
    const int* __restrict__ topk_idx, const int* __restrict__ idx_cluster, int* __restrict__ kmap)
{
  const int n = blockIdx.y; const int i = blockIdx.x * 256 + threadIdx.x;
  if (i >= SS) return;
  kmap[n * HWP + topk_idx[n * SS + i]] = idx_cluster[n * SS + i];
}

// ---------------- K11: ego flags --------------------------------------------
__global__ void k_ego(const int* __restrict__ record_len, int R, int* __restrict__ ego) {
  if (threadIdx.x == 0 && blockIdx.x == 0) {
    int acc = 0;
    for (int r = 0; r < R; ++r) {
      if (acc >= 0 && acc < NN) ego[acc] = 1;
      acc += record_len[r];
    }
  }
}

// ---------------- K12: final output (float4) --------------------------------
__global__ __launch_bounds__(256) void k_output(
    const float* __restrict__ x, const float* __restrict__ merged,
    const int* __restrict__ kmap, const int* __restrict__ ego, float* __restrict__ out)
{
  const int n = blockIdx.z, c = blockIdx.y;
  const int p4 = blockIdx.x * 256 + threadIdx.x;
  if (p4 >= HWP / 4) return;
  const size_t base = (size_t)(n * CCH + c) * HWP + 4 * p4;
  float4 v;
  if (ego[n]) {
    v = *(const float4*)&x[base];
  } else {
    int4 k4 = *(const int4*)&kmap[n * HWP + 4 * p4];
    const float* mb = &merged[(size_t)n * KCL * CCH + c];
    v.x = (k4.x >= 0) ? mb[(size_t)k4.x * CCH] : 0.f;
    v.y = (k4.y >= 0) ? mb[(size_t)k4.y * CCH] : 0.f;
    v.z = (k4.z >= 0) ? mb[(size_t)k4.z * CCH] : 0.f;
    v.w = (k4.w >= 0) ? mb[(size_t)k4.w * CCH] : 0.f;
  }
  *(float4*)&out[base] = v;
}

// ---------------- launch -----------------------------------------------------
extern "C" void kernel_launch(void* const* d_in, const int* in_sizes, int n_in,
                              void* d_out, int out_size, void* d_ws, size_t ws_size,
                              hipStream_t stream)
{
  const float* x   = (const float*)d_in[0];
  const float* w1  = (const float*)d_in[1];
  const float* b1  = (const float*)d_in[2];
  const float* w2  = (const float*)d_in[3];
  const float* b2  = (const float*)d_in[4];
  const float* pri = (const float*)d_in[5];
  const int*   rec = (const int*)d_in[6];
  const int R = in_sizes[6];
  float* out = (float*)d_out;

  char* ws = (char*)d_ws;
  size_t off = 0;
  auto alloc = [&](size_t bytes) -> char* {
    char* p = ws + off;
    off = (off + bytes + 255) & ~(size_t)255;
    return p;
  };
  float* scores      = (float*)alloc(sizeof(float) * NN * HWP);
  int*   topk_idx    = (int*)  alloc(sizeof(int)   * NN * SS);
  float* conf        = (float*)alloc(sizeof(float) * NN * SS);
  float* tokens      = (float*)alloc(sizeof(float) * (size_t)NN * SS * CCH);
  float* tokensT     = (float*)alloc(sizeof(float) * (size_t)NN * CCH * SS);
  float* w1T         = (float*)alloc(sizeof(float) * CCH * CCH);
  float* sq          = (float*)alloc(sizeof(float) * NN * SS);
  float* density     = (float*)alloc(sizeof(float) * NN * SS);
  float* cscore      = (float*)alloc(sizeof(float) * NN * SS);
  int*   d2max       = (int*)  alloc(sizeof(int)   * NN);
  int*   index_down  = (int*)  alloc(sizeof(int)   * NN * KCL);
  int*   idx_cluster = (int*)  alloc(sizeof(int)   * NN * SS);
  float* all_w       = (float*)alloc(sizeof(float) * NN * KCL);
  float* merged      = (float*)alloc(sizeof(float) * (size_t)NN * KCL * CCH);
  int*   kmap        = (int*)  alloc(sizeof(int)   * NN * HWP);
  int*   ego         = (int*)  alloc(sizeof(int)   * NN);
  float* d2          = (float*)alloc(sizeof(float) * (size_t)NN * SS * SS);
  if (off > ws_size)
    fprintf(stderr, "ERMVP kernel: workspace too small: need %zu, have %zu\n", off, ws_size);

  hipMemsetAsync(d2max, 0, sizeof(int) * NN, stream);
  hipMemsetAsync(all_w, 0, sizeof(float) * NN * KCL, stream);
  hipMemsetAsync(merged, 0, sizeof(float) * (size_t)NN * KCL * CCH, stream);
  hipMemsetAsync(kmap, 0xFF, sizeof(int) * NN * HWP, stream);
  hipMemsetAsync(ego, 0, sizeof(int) * NN, stream);

  k_w1t<<<dim3(8, 8), dim3(32, 8), 0, stream>>>(w1, w1T);
  k_score<<<dim3((HWP + 63) / 64, NN), 256, 0, stream>>>(x, w1T, b1, w2, b2, pri, scores);
  k_topk_sample<<<NN, 1024, 0, stream>>>(scores, topk_idx, conf);
  k_gather_ln<<<dim3(SS, NN), 256, 0, stream>>>(x, topk_idx, conf, tokens, sq);
  k_ttrans<<<dim3((SS + 63) / 64, CCH / 64, NN), 256, 0, stream>>>(tokens, tokensT);
  k_gram<<<dim3(20, 20, NN), 256, 0, stream>>>(tokensT, sq, d2, d2max);
  k_knn<<<dim3(SS / 4, NN), 256, 0, stream>>>(d2, density);
  k_parent<<<dim3(SS, NN), 256, 0, stream>>>(d2, density, d2max, cscore);
  k_topk_centers<<<NN, 1024, 0, stream>>>(cscore, index_down);
  k_assign<<<dim3((SS + 255) / 256, NN), 256, 0, stream>>>(d2, index_down, idx_cluster);
  k_center_overwrite<<<NN, 320, 0, stream>>>(index_down, idx_cluster);
  k_weights<<<dim3((SS + 255) / 256, NN), 256, 0, stream>>>(idx_cluster, conf, all_w);
  k_merge<<<dim3(SS, NN), 256, 0, stream>>>(idx_cluster, conf, all_w, tokens, merged);
  k_kmap<<<dim3((SS + 255) / 256, NN), 256, 0, stream>>>(topk_idx, idx_cluster, kmap);
  k_ego<<<1, 64, 0, stream>>>(rec, R, ego);
  k_output<<<dim3((HWP / 4 + 255) / 256, CCH, NN), 256, 0, stream>>>(x, merged, kmap, ego, out);
}

// Round 4
// 1210.791 us; speedup vs baseline: 1.5266x; 1.2988x over previous
//
#include <hip/hip_runtime.h>
#include <cstdio>
#include <cstdint>

#define NN  8
#define CCH 256
#define HWP 25200
#define SS  2520
#define KCL 315
#define KNN 10

__device__ __forceinline__ unsigned fmap(float f) {
  unsigned u = __float_as_uint(f);
  return (u & 0x80000000u) ? ~u : (u | 0x80000000u);
}

// ---------------- K-1: transpose w1 [d][c] -> w1T [c][d] --------------------
__global__ __launch_bounds__(256) void k_w1t(const float* __restrict__ w1, float* __restrict__ w1T) {
  __shared__ float tile[32][33];
  const int bx = blockIdx.x * 32, by = blockIdx.y * 32;
  const int tx = threadIdx.x, ty = threadIdx.y;  // 32 x 8
  for (int r = 0; r < 32; r += 8)
    tile[ty + r][tx] = w1[(by + ty + r) * CCH + bx + tx];
  __syncthreads();
  for (int r = 0; r < 32; r += 8)
    w1T[(bx + ty + r) * CCH + by + tx] = tile[tx][ty + r];
}

// ---------------- K0: score net (64px x 256d tile GEMM) ---------------------
// R0 structure, byte-exact: 8x8 thread tile, conflict-free LDS patterns,
// single-buffered staging. Measured 338us / VALUBusy 67% / occ 29% — the
// LDS-port/VALU balance point; R1-R3 restructures all regressed.
__global__ __launch_bounds__(256) void k_score(
    const float* __restrict__ x, const float* __restrict__ w1T,
    const float* __restrict__ b1, const float* __restrict__ w2,
    const float* __restrict__ b2, const float* __restrict__ pri,
    float* __restrict__ scores)
{
  __shared__ float Wl[16 * 256];   // [kk][d]
  __shared__ float Xl[16 * 64];    // [kk][p]
  __shared__ float red[64 * 33];
  const int n = blockIdx.y, p0 = blockIdx.x * 64, tid = threadIdx.x;
  const int dt = tid & 31, pt = tid >> 5;
  float acc[8][8];
#pragma unroll
  for (int i = 0; i < 8; ++i)
#pragma unroll
    for (int j = 0; j < 8; ++j) acc[i][j] = 0.f;

  for (int c0 = 0; c0 < CCH; c0 += 16) {
    // stage W: flat contiguous copy (no transpose needed)
    {
      const float4* src = (const float4*)(w1T + (size_t)c0 * CCH);
      float4* dst = (float4*)Wl;
#pragma unroll
      for (int i = 0; i < 4; ++i) dst[tid + 256 * i] = src[tid + 256 * i];
    }
    // stage X: [kk][64p]
    {
      int kk = tid >> 4, q = tid & 15;
      int gp = p0 + 4 * q; if (gp > HWP - 4) gp = HWP - 4;
      *(float4*)&Xl[kk * 64 + 4 * q] = *(const float4*)&x[(size_t)(n * CCH + c0 + kk) * HWP + gp];
    }
    __syncthreads();
#pragma unroll
    for (int kk = 0; kk < 16; ++kk) {
      const float4 w0 = *(const float4*)&Wl[kk * 256 + 4 * dt];
      const float4 w1v = *(const float4*)&Wl[kk * 256 + 128 + 4 * dt];
      const float4 x0 = *(const float4*)&Xl[kk * 64 + 4 * pt];
      const float4 x1 = *(const float4*)&Xl[kk * 64 + 32 + 4 * pt];
      const float a[8] = {w0.x, w0.y, w0.z, w0.w, w1v.x, w1v.y, w1v.z, w1v.w};
      const float b[8] = {x0.x, x0.y, x0.z, x0.w, x1.x, x1.y, x1.z, x1.w};
#pragma unroll
      for (int di = 0; di < 8; ++di)
#pragma unroll
        for (int pj = 0; pj < 8; ++pj) acc[di][pj] += a[di] * b[pj];
    }
    __syncthreads();
  }
  // epilogue: relu + dot with w2 over this thread's 8 d's
  float part[8];
#pragma unroll
  for (int pj = 0; pj < 8; ++pj) part[pj] = 0.f;
#pragma unroll
  for (int di = 0; di < 8; ++di) {
    int d = (di < 4) ? (4 * dt + di) : (128 + 4 * dt + di - 4);
    float bb = b1[d], wv = w2[d];
#pragma unroll
    for (int pj = 0; pj < 8; ++pj) {
      float h = acc[di][pj] + bb; h = h > 0.f ? h : 0.f;
      part[pj] += h * wv;
    }
  }
#pragma unroll
  for (int pj = 0; pj < 8; ++pj) {
    int px = (pj < 4) ? (4 * pt + pj) : (32 + 4 * pt + pj - 4);
    red[px * 33 + dt] = part[pj];
  }
  __syncthreads();
  if (tid < 64) {
    float s = b2[0];
#pragma unroll
    for (int g = 0; g < 32; ++g) s += red[tid * 33 + g];
    float sc = 1.f / (1.f + expf(-s));
    int p = p0 + tid;
    if (p < HWP) scores[n * HWP + p] = sc * pri[n * HWP + p];
  }
}

// ---------------- K1: exact top-S sample (radix select + ordered compaction)
// No bitonic sort. Scores cached in dynamic LDS (one global read). Tokens
// emitted in ASCENDING p order: same selected set as score-desc top-k, with
// ties at the threshold taken smallest-p-first (== jax stable tie-break).
// Downstream is permutation-invariant over the token axis; spatial order
// additionally gives k_gather_ln L2 locality.
__global__ __launch_bounds__(1024) void k_topk_sample(
    const float* __restrict__ scores, int* __restrict__ topk_idx, float* __restrict__ conf)
{
  extern __shared__ float sc_lds[];          // HWP floats (100.8 KB)
  __shared__ unsigned hist[256];
  __shared__ int wcnt[16], woff[16];
  __shared__ int sh_base, sh_tbase, sh_ngt;
  __shared__ unsigned sh_rank, sh_chosen;
  const int n = blockIdx.x, tid = threadIdx.x;
  const int lane = tid & 63, w = tid >> 6;

  // cache scores (vectorized)
  {
    const float4* src = (const float4*)(scores + (size_t)n * HWP);
    float4* dst = (float4*)sc_lds;
    for (int i = tid; i < HWP / 4; i += 1024) dst[i] = src[i];
  }
  if (tid == 0) { sh_rank = SS; sh_ngt = 0; sh_base = 0; sh_tbase = 0; }
  __syncthreads();

  // 4-pass radix select for uT = SS-th largest
  unsigned prefix = 0, pmask = 0;
  for (int shift = 24; shift >= 0; shift -= 8) {
    if (tid < 256) hist[tid] = 0;
    __syncthreads();
    for (int e = tid; e < HWP; e += 1024) {
      unsigned u = fmap(sc_lds[e]);
      if ((u & pmask) == prefix) atomicAdd(&hist[(u >> shift) & 255u], 1u);
    }
    __syncthreads();
    if (tid == 0) {
      unsigned r = sh_rank, chosen = 0;
      for (int b = 255; b >= 0; --b) {
        unsigned cb = hist[b];
        if (cb < r) r -= cb; else { chosen = (unsigned)b; break; }
      }
      sh_rank = r; sh_chosen = chosen;
    }
    __syncthreads();
    prefix |= sh_chosen << shift;
    pmask  |= 0xFFu << shift;
    __syncthreads();
  }
  const unsigned uT = prefix;

  // count strictly-greater
  {
    int myg = 0;
    for (int e = tid; e < HWP; e += 1024) myg += (fmap(sc_lds[e]) > uT);
#pragma unroll
    for (int o = 32; o > 0; o >>= 1) myg += __shfl_down(myg, o);
    if (lane == 0) atomicAdd(&sh_ngt, myg);
  }
  __syncthreads();
  const int T = SS - sh_ngt;   // tie budget (>=1)

  // ordered compaction in p order
  for (int c0 = 0; c0 < HWP; c0 += 1024) {
    const int e = c0 + tid;
    const bool valid = e < HWP;
    const float s = valid ? sc_lds[e] : 0.f;
    const unsigned u = valid ? fmap(s) : 0u;
    const bool tie = valid && (u == uT);
    const bool gt  = valid && (u > uT);
    unsigned long long mt = __ballot(tie);
    if (lane == 0) wcnt[w] = __popcll(mt);
    __syncthreads();
    if (tid == 0) {
      int run = sh_tbase;
      for (int q = 0; q < 16; ++q) { woff[q] = run; run += wcnt[q]; }
      sh_tbase = run;
    }
    __syncthreads();
    const int trank = woff[w] + __popcll(mt & ((1ULL << lane) - 1ULL));
    const bool sel = gt || (tie && trank < T);
    unsigned long long ms = __ballot(sel);
    if (lane == 0) wcnt[w] = __popcll(ms);
    __syncthreads();
    if (tid == 0) {
      int run = sh_base;
      for (int q = 0; q < 16; ++q) { woff[q] = run; run += wcnt[q]; }
      sh_base = run;
    }
    __syncthreads();
    if (sel) {
      int pos = woff[w] + __popcll(ms & ((1ULL << lane) - 1ULL));
      topk_idx[n * SS + pos] = e;
      conf[n * SS + pos] = s;
    }
    __syncthreads();
  }
}

// ---------------- reductions ------------------------------------------------
__device__ __forceinline__ float block_sum256(float v, float* scratch) {
#pragma unroll
  for (int o = 32; o > 0; o >>= 1) v += __shfl_down(v, o);
  int wid = threadIdx.x >> 6, lane = threadIdx.x & 63;
  if (lane == 0) scratch[wid] = v;
  __syncthreads();
  float r = scratch[0] + scratch[1] + scratch[2] + scratch[3];
  __syncthreads();
  return r;
}

// ---------------- K2: gather + layernorm + conf + sq ------------------------
__global__ __launch_bounds__(256) void k_gather_ln(
    const float* __restrict__ x, const int* __restrict__ topk_idx,
    const float* __restrict__ conf, float* __restrict__ tokens, float* __restrict__ sq)
{
  __shared__ float scratch[4];
  const int t = blockIdx.x, n = blockIdx.y, c = threadIdx.x;
  const int p = topk_idx[n * SS + t];
  float v = x[(size_t)(n * CCH + c) * HWP + p];
  float mu = block_sum256(v, scratch) * (1.f / CCH);
  float d = v - mu;
  float var = block_sum256(d * d, scratch) * (1.f / CCH);
  float inv = 1.f / sqrtf(var + 1e-5f);
  float tok = d * inv * conf[n * SS + t];
  tokens[(size_t)(n * SS + t) * CCH + c] = tok;
  float s2 = block_sum256(tok * tok, scratch);
  if (c == 0) sq[n * SS + t] = s2;
}

// ---------------- K2b: transpose tokens [n][t][c] -> tokensT [n][c][t] ------
__global__ __launch_bounds__(256) void k_ttrans(
    const float* __restrict__ tokens, float* __restrict__ tokensT)
{
  __shared__ float tile[64][68];
  const int n = blockIdx.z, t0 = blockIdx.x * 64, cc0 = blockIdx.y * 64;
  const int tid = threadIdx.x;
  for (int l = tid; l < 1024; l += 256) {
    int tr = l >> 4, q = l & 15;
    int gt = t0 + tr;
    float4 v = {0.f, 0.f, 0.f, 0.f};
    if (gt < SS) v = *(const float4*)&tokens[(size_t)(n * SS + gt) * CCH + cc0 + 4 * q];
    *(float4*)&tile[tr][4 * q] = v;
  }
  __syncthreads();
  for (int l = tid; l < 1024; l += 256) {
    int cr = l >> 4, q = l & 15;
    int gt = t0 + 4 * q;
    if (gt <= SS - 4) {
      float4 v;
      v.x = tile[4 * q + 0][cr]; v.y = tile[4 * q + 1][cr];
      v.z = tile[4 * q + 2][cr]; v.w = tile[4 * q + 3][cr];
      *(float4*)&tokensT[(size_t)(n * CCH + cc0 + cr) * SS + gt] = v;
    }
  }
}

// ---------------- K3: gram GEMM -> d2 (symmetric, upper blocks only) --------
// R0 structure, byte-exact (single-buffered LDS staging).
__global__ __launch_bounds__(256) void k_gram(
    const float* __restrict__ tokensT, const float* __restrict__ sq,
    float* __restrict__ d2, int* __restrict__ d2max)
{
  const int bi = blockIdx.y, bj = blockIdx.x, n = blockIdx.z;
  if (bj < bi) return;
  __shared__ float Al[16 * 128], Bl[16 * 128];
  __shared__ float redm[256];
  const int i0 = bi * 128, j0 = bj * 128, tid = threadIdx.x;
  const int ti = tid & 15, tj = tid >> 4;
  float acc[8][8];
#pragma unroll
  for (int i = 0; i < 8; ++i)
#pragma unroll
    for (int j = 0; j < 8; ++j) acc[i][j] = 0.f;

  for (int c0 = 0; c0 < CCH; c0 += 16) {
#pragma unroll
    for (int l0 = 0; l0 < 2; ++l0) {
      int l = threadIdx.x + 256 * l0;
      int kk = l >> 5, q = l & 31;
      size_t srow = (size_t)(n * CCH + c0 + kk) * SS;
      float4 z = {0.f, 0.f, 0.f, 0.f};
      int gi = i0 + 4 * q;
      *(float4*)&Al[kk * 128 + 4 * q] = (gi <= SS - 4) ? *(const float4*)&tokensT[srow + gi] : z;
      int gj = j0 + 4 * q;
      *(float4*)&Bl[kk * 128 + 4 * q] = (gj <= SS - 4) ? *(const float4*)&tokensT[srow + gj] : z;
    }
    __syncthreads();
#pragma unroll
    for (int kk = 0; kk < 16; ++kk) {
      const float4 a0 = *(const float4*)&Al[kk * 128 + 4 * ti];
      const float4 a1 = *(const float4*)&Al[kk * 128 + 64 + 4 * ti];
      const float4 b0 = *(const float4*)&Bl[kk * 128 + 4 * tj];
      const float4 b1 = *(const float4*)&Bl[kk * 128 + 64 + 4 * tj];
      const float a[8] = {a0.x, a0.y, a0.z, a0.w, a1.x, a1.y, a1.z, a1.w};
      const float b[8] = {b0.x, b0.y, b0.z, b0.w, b1.x, b1.y, b1.z, b1.w};
#pragma unroll
      for (int ii = 0; ii < 8; ++ii)
#pragma unroll
        for (int jj = 0; jj < 8; ++jj) acc[ii][jj] += a[ii] * b[jj];
    }
    __syncthreads();
  }
  int gi[8], gj[8];
  float sqi[8], sqj[8];
#pragma unroll
  for (int ii = 0; ii < 8; ++ii) {
    gi[ii] = i0 + ((ii < 4) ? (4 * ti + ii) : (64 + 4 * ti + ii - 4));
    sqi[ii] = (gi[ii] < SS) ? sq[n * SS + gi[ii]] : 0.f;
    gj[ii] = j0 + ((ii < 4) ? (4 * tj + ii) : (64 + 4 * tj + ii - 4));
    sqj[ii] = (gj[ii] < SS) ? sq[n * SS + gj[ii]] : 0.f;
  }
  float outv[8][8];
  float mx = -3e38f;
#pragma unroll
  for (int ii = 0; ii < 8; ++ii)
#pragma unroll
    for (int jj = 0; jj < 8; ++jj) {
      float o = sqi[ii] + sqj[jj] - 2.f * acc[ii][jj];
      outv[ii][jj] = o;
      if (gi[ii] < SS && gj[jj] < SS) mx = fmaxf(mx, o);
    }
#pragma unroll
  for (int ii = 0; ii < 8; ++ii) {
    if (gi[ii] < SS) {
      size_t row = (size_t)(n * SS + gi[ii]) * SS;
      int jb0 = j0 + 4 * tj;
      float4 o0 = {outv[ii][0], outv[ii][1], outv[ii][2], outv[ii][3]};
      *(float4*)&d2[row + jb0] = o0;
      int jb1 = j0 + 64 + 4 * tj;
      if (jb1 < SS) {
        float4 o1 = {outv[ii][4], outv[ii][5], outv[ii][6], outv[ii][7]};
        *(float4*)&d2[row + jb1] = o1;
      }
    }
  }
  if (bi != bj) {
#pragma unroll
    for (int jj = 0; jj < 8; ++jj) {
      if (gj[jj] < SS) {
        size_t row = (size_t)(n * SS + gj[jj]) * SS;
        int ib0 = i0 + 4 * ti;
        float4 m0 = {outv[0][jj], outv[1][jj], outv[2][jj], outv[3][jj]};
        *(float4*)&d2[row + ib0] = m0;
        int ib1 = i0 + 64 + 4 * ti;
        if (ib1 < SS) {
          float4 m1 = {outv[4][jj], outv[5][jj], outv[6][jj], outv[7][jj]};
          *(float4*)&d2[row + ib1] = m1;
        }
      }
    }
  }
  redm[tid] = mx; __syncthreads();
  for (int s = 128; s > 0; s >>= 1) {
    if (tid < s) redm[tid] = fmaxf(redm[tid], redm[tid + s]);
    __syncthreads();
  }
  if (tid == 0) atomicMax(&d2max[n], __float_as_int(redm[0]));
}

// ---------------- K4: KNN density (wave per row, register top-10) -----------
__global__ __launch_bounds__(256) void k_knn(
    const float* __restrict__ d2, float* __restrict__ density)
{
  const int n = blockIdx.y;
  const int w = threadIdx.x >> 6, lane = threadIdx.x & 63;
  const int i = blockIdx.x * 4 + w;
  const float* dr = &d2[(size_t)(n * SS + i) * SS];
  float s[KNN];
#pragma unroll
  for (int k = 0; k < KNN; ++k) s[k] = 3e38f;
  for (int e = lane; e < SS; e += 64) {
    float t = dr[e];
#pragma unroll
    for (int k = 0; k < KNN; ++k) {
      float lo = fminf(s[k], t);
      t = fmaxf(s[k], t);
      s[k] = lo;
    }
  }
  float sum = 0.f;
  for (int r = 0; r < KNN; ++r) {
    float m = s[0];
#pragma unroll
    for (int o = 32; o > 0; o >>= 1) m = fminf(m, __shfl_xor(m, o));
    unsigned long long msk = __ballot(s[0] == m);
    int first = __ffsll(msk) - 1;
    if (lane == first) {
#pragma unroll
      for (int k = 0; k < KNN - 1; ++k) s[k] = s[k + 1];
      s[KNN - 1] = 3e38f;
    }
    sum += fmaxf(m, 1e-12f);
  }
  if (lane == 0) density[n * SS + i] = expf(-sum * (1.f / (KNN * CCH)));
}

// ---------------- K5: parent dist + cscore ----------------------------------
__global__ __launch_bounds__(256) void k_parent(
    const float* __restrict__ d2, const float* __restrict__ density,
    const int* __restrict__ d2max, float* __restrict__ cscore)
{
  __shared__ float swv[4];
  const int i = blockIdx.x, n = blockIdx.y, tid = threadIdx.x;
  const float di = density[n * SS + i];
  const float* dr = &d2[(size_t)(n * SS + i) * SS];
  float m = 3e38f;
  for (int e = tid; e < SS; e += 256) {
    float dj = density[n * SS + e];
    float v = dr[e];
    if (dj > di && v < m) m = v;
  }
#pragma unroll
  for (int o = 32; o > 0; o >>= 1) m = fminf(m, __shfl_down(m, o));
  int wid = tid >> 6, lane = tid & 63;
  if (lane == 0) swv[wid] = m;
  __syncthreads();
  if (tid == 0) {
    float mm = fminf(fminf(swv[0], swv[1]), fminf(swv[2], swv[3]));
    mm = fminf(mm, __int_as_float(d2max[n]));
    float pd = sqrtf(fmaxf(mm, 1e-12f)) * 0.0625f;
    cscore[n * SS + i] = pd * di;
  }
}

// ---------------- K6: top-K cluster centers (radix + ordered compaction) ----
// Same machinery as k_topk_sample over SS elements, rank KCL. index_down in
// ascending token order -> consistent cluster relabeling, output-invariant.
__global__ __launch_bounds__(1024) void k_topk_centers(
    const float* __restrict__ cscore, int* __restrict__ index_down)
{
  __shared__ float cs_lds[SS];               // 10.1 KB
  __shared__ unsigned hist[256];
  __shared__ int wcnt[16], woff[16];
  __shared__ int sh_base, sh_tbase, sh_ngt;
  __shared__ unsigned sh_rank, sh_chosen;
  const int n = blockIdx.x, tid = threadIdx.x;
  const int lane = tid & 63, w = tid >> 6;

  for (int e = tid; e < SS; e += 1024) cs_lds[e] = cscore[n * SS + e];
  if (tid == 0) { sh_rank = KCL; sh_ngt = 0; sh_base = 0; sh_tbase = 0; }
  __syncthreads();

  unsigned prefix = 0, pmask = 0;
  for (int shift = 24; shift >= 0; shift -= 8) {
    if (tid < 256) hist[tid] = 0;
    __syncthreads();
    for (int e = tid; e < SS; e += 1024) {
      unsigned u = fmap(cs_lds[e]);
      if ((u & pmask) == prefix) atomicAdd(&hist[(u >> shift) & 255u], 1u);
    }
    __syncthreads();
    if (tid == 0) {
      unsigned r = sh_rank, chosen = 0;
      for (int b = 255; b >= 0; --b) {
        unsigned cb = hist[b];
        if (cb < r) r -= cb; else { chosen = (unsigned)b; break; }
      }
      sh_rank = r; sh_chosen = chosen;
    }
    __syncthreads();
    prefix |= sh_chosen << shift;
    pmask  |= 0xFFu << shift;
    __syncthreads();
  }
  const unsigned uT = prefix;

  {
    int myg = 0;
    for (int e = tid; e < SS; e += 1024) myg += (fmap(cs_lds[e]) > uT);
#pragma unroll
    for (int o = 32; o > 0; o >>= 1) myg += __shfl_down(myg, o);
    if (lane == 0) atomicAdd(&sh_ngt, myg);
  }
  __syncthreads();
  const int T = KCL - sh_ngt;

  for (int c0 = 0; c0 < SS; c0 += 1024) {
    const int e = c0 + tid;
    const bool valid = e < SS;
    const unsigned u = valid ? fmap(cs_lds[e]) : 0u;
    const bool tie = valid && (u == uT);
    const bool gt  = valid && (u > uT);
    unsigned long long mt = __ballot(tie);
    if (lane == 0) wcnt[w] = __popcll(mt);
    __syncthreads();
    if (tid == 0) {
      int run = sh_tbase;
      for (int q = 0; q < 16; ++q) { woff[q] = run; run += wcnt[q]; }
      sh_tbase = run;
    }
    __syncthreads();
    const int trank = woff[w] + __popcll(mt & ((1ULL << lane) - 1ULL));
    const bool sel = gt || (tie && trank < T);
    unsigned long long ms = __ballot(sel);
    if (lane == 0) wcnt[w] = __popcll(ms);
    __syncthreads();
    if (tid == 0) {
      int run = sh_base;
      for (int q = 0; q < 16; ++q) { woff[q] = run; run += wcnt[q]; }
      sh_base = run;
    }
    __syncthreads();
    if (sel) {
      int pos = woff[w] + __popcll(ms & ((1ULL << lane) - 1ULL));
      index_down[n * KCL + pos] = e;
    }
    __syncthreads();
  }
}

// ---------------- K7: assignment + center overwrite + weights + kmap --------
__global__ __launch_bounds__(256) void k_assign(
    const float* __restrict__ d2, const int* __restrict__ index_down,
    const float* __restrict__ conf, const int* __restrict__ topk_idx,
    int* __restrict__ idx_cluster, float* __restrict__ all_w, int* __restrict__ kmap)
{
  const int n = blockIdx.y;
  const int i = blockIdx.x * 256 + threadIdx.x;
  if (i >= SS) return;
  float best = 3e38f; int bk = 0, forced = -1;
  for (int k = 0; k < KCL; ++k) {
    int r = index_down[n * KCL + k];
    if (r == i) forced = k;
    float v = d2[(size_t)(n * SS + r) * SS + i];
    if (v < best) { best = v; bk = k; }
  }
  if (forced >= 0) bk = forced;
  idx_cluster[n * SS + i] = bk;
  atomicAdd(&all_w[n * KCL + bk], conf[n * SS + i]);
  kmap[n * HWP + topk_idx[n * SS + i]] = bk;
}

// ---------------- K9: merge --------------------------------------------------
__global__ __launch_bounds__(256) void k_merge(
    const int* __restrict__ idx_cluster, const float* __restrict__ conf,
    const float* __restrict__ all_w, const float* __restrict__ tokens, float* __restrict__ merged)
{
  const int t = blockIdx.x, n = blockIdx.y, c = threadIdx.x;
  const int k = idx_cluster[n * SS + t];
  const float w = conf[n * SS + t] / (all_w[n * KCL + k] + 1e-6f);
  atomicAdd(&merged[(size_t)(n * KCL + k) * CCH + c],
            tokens[(size_t)(n * SS + t) * CCH + c] * w);
}

// ---------------- K12: final output (float4, ego computed inline) -----------
__global__ __launch_bounds__(256) void k_output(
    const float* __restrict__ x, const float* __restrict__ merged,
    const int* __restrict__ kmap, const int* __restrict__ rec, int R,
    float* __restrict__ out)
{
  const int n = blockIdx.z, c = blockIdx.y;
  const int p4 = blockIdx.x * 256 + threadIdx.x;
  if (p4 >= HWP / 4) return;
  bool ego = false;
  {
    int acc = 0;
    for (int r = 0; r < R; ++r) { if (acc == n) ego = true; acc += rec[r]; }
  }
  const size_t base = (size_t)(n * CCH + c) * HWP + 4 * p4;
  float4 v;
  if (ego) {
    v = *(const float4*)&x[base];
  } else {
    int4 k4 = *(const int4*)&kmap[n * HWP + 4 * p4];
    const float* mb = &merged[(size_t)n * KCL * CCH + c];
    v.x = (k4.x >= 0) ? mb[(size_t)k4.x * CCH] : 0.f;
    v.y = (k4.y >= 0) ? mb[(size_t)k4.y * CCH] : 0.f;
    v.z = (k4.z >= 0) ? mb[(size_t)k4.z * CCH] : 0.f;
    v.w = (k4.w >= 0) ? mb[(size_t)k4.w * CCH] : 0.f;
  }
  *(float4*)&out[base] = v;
}

// ---------------- launch -----------------------------------------------------
extern "C" void kernel_launch(void* const* d_in, const int* in_sizes, int n_in,
                              void* d_out, int out_size, void* d_ws, size_t ws_size,
                              hipStream_t stream)
{
  const float* x   = (const float*)d_in[0];
  const float* w1  = (const float*)d_in[1];
  const float* b1  = (const float*)d_in[2];
  const float* w2  = (const float*)d_in[3];
  const float* b2  = (const float*)d_in[4];
  const float* pri = (const float*)d_in[5];
  const int*   rec = (const int*)d_in[6];
  const int R = in_sizes[6];
  float* out = (float*)d_out;

  char* ws = (char*)d_ws;
  size_t off = 0;
  auto alloc = [&](size_t bytes) -> char* {
    char* p = ws + off;
    off = (off + bytes + 255) & ~(size_t)255;
    return p;
  };
  float* scores      = (float*)alloc(sizeof(float) * NN * HWP);
  int*   topk_idx    = (int*)  alloc(sizeof(int)   * NN * SS);
  float* conf        = (float*)alloc(sizeof(float) * NN * SS);
  float* tokens      = (float*)alloc(sizeof(float) * (size_t)NN * SS * CCH);
  float* tokensT     = (float*)alloc(sizeof(float) * (size_t)NN * CCH * SS);
  float* w1T         = (float*)alloc(sizeof(float) * CCH * CCH);
  float* sq          = (float*)alloc(sizeof(float) * NN * SS);
  float* density     = (float*)alloc(sizeof(float) * NN * SS);
  float* cscore      = (float*)alloc(sizeof(float) * NN * SS);
  int*   d2max       = (int*)  alloc(sizeof(int)   * NN);
  int*   index_down  = (int*)  alloc(sizeof(int)   * NN * KCL);
  int*   idx_cluster = (int*)  alloc(sizeof(int)   * NN * SS);
  float* all_w       = (float*)alloc(sizeof(float) * NN * KCL);
  float* merged      = (float*)alloc(sizeof(float) * (size_t)NN * KCL * CCH);
  int*   kmap        = (int*)  alloc(sizeof(int)   * NN * HWP);
  float* d2          = (float*)alloc(sizeof(float) * (size_t)NN * SS * SS);
  if (off > ws_size)
    fprintf(stderr, "ERMVP kernel: workspace too small: need %zu, have %zu\n", off, ws_size);

  hipMemsetAsync(d2max, 0, sizeof(int) * NN, stream);
  hipMemsetAsync(all_w, 0, sizeof(float) * NN * KCL, stream);
  hipMemsetAsync(merged, 0, sizeof(float) * (size_t)NN * KCL * CCH, stream);
  hipMemsetAsync(kmap, 0xFF, sizeof(int) * NN * HWP, stream);

  k_w1t<<<dim3(8, 8), dim3(32, 8), 0, stream>>>(w1, w1T);
  k_score<<<dim3((HWP + 63) / 64, NN), 256, 0, stream>>>(x, w1T, b1, w2, b2, pri, scores);
  k_topk_sample<<<NN, 1024, sizeof(float) * HWP, stream>>>(scores, topk_idx, conf);
  k_gather_ln<<<dim3(SS, NN), 256, 0, stream>>>(x, topk_idx, conf, tokens, sq);
  k_ttrans<<<dim3((SS + 63) / 64, CCH / 64, NN), 256, 0, stream>>>(tokens, tokensT);
  k_gram<<<dim3(20, 20, NN), 256, 0, stream>>>(tokensT, sq, d2, d2max);
  k_knn<<<dim3(SS / 4, NN), 256, 0, stream>>>(d2, density);
  k_parent<<<dim3(SS, NN), 256, 0, stream>>>(d2, density, d2max, cscore);
  k_topk_centers<<<NN, 1024, 0, stream>>>(cscore, index_down);
  k_assign<<<dim3((SS + 255) / 256, NN), 256, 0, stream>>>(d2, index_down, conf, topk_idx,
                                                           idx_cluster, all_w, kmap);
  k_merge<<<dim3(SS, NN), 256, 0, stream>>>(idx_cluster, conf, all_w, tokens, merged);
  k_output<<<dim3((HWP / 4 + 255) / 256, CCH, NN), 256, 0, stream>>>(x, merged, kmap, rec, R, out);
}